// Round 18
// baseline (190.529 us; speedup 1.0000x reference)
//
#include <hip/hip_runtime.h>

#define B_TOTAL 8192
#define T_FULL  100
#define XD      256
#define T0      30
#define TW      70      // time window length (30:100)
#define KS      50      // conv kernel size
#define NT      21      // TW - KS + 1 output positions
#define YOUT    300     // Y_DIM * 50
#define FC_NB   16      // batches per FC block
#define NF4     (TW * XD / 4)   // 4480 float4 per window

// native clang vector type: __builtin_nontemporal_load rejects HIP's
// float4 class (round-17 compile failure) but accepts ext_vector_type.
typedef float f4v __attribute__((ext_vector_type(4)));

// ---------------- named-scalar conv machinery (no arrays, no allocas) -------

#define DECLG(G) float G##0,G##1,G##2,G##3,G##4,G##5,G##6,G##7,G##8,G##9;

// ds_read a 10-row decade from the LDS window (lanes consecutive -> 2/bank = free)
#define LOADL(G, R0) \
  G##0=ldsx[(R0+0)*XD+tid]; G##1=ldsx[(R0+1)*XD+tid]; G##2=ldsx[(R0+2)*XD+tid]; \
  G##3=ldsx[(R0+3)*XD+tid]; G##4=ldsx[(R0+4)*XD+tid]; G##5=ldsx[(R0+5)*XD+tid]; \
  G##6=ldsx[(R0+6)*XD+tid]; G##7=ldsx[(R0+7)*XD+tid]; G##8=ldsx[(R0+8)*XD+tid]; \
  G##9=ldsx[(R0+9)*XD+tid];

#define LOADWSET(W, K0) \
  W##0=wtp[(K0+0)*XD]; W##1=wtp[(K0+1)*XD]; W##2=wtp[(K0+2)*XD]; W##3=wtp[(K0+3)*XD]; W##4=wtp[(K0+4)*XD]; \
  W##5=wtp[(K0+5)*XD]; W##6=wtp[(K0+6)*XD]; W##7=wtp[(K0+7)*XD]; W##8=wtp[(K0+8)*XD]; W##9=wtp[(K0+9)*XD];

#define ROW(A, W, X0,X1,X2,X3,X4,X5,X6,X7,X8,X9) \
  A=fmaf(X0,W##0,A); A=fmaf(X1,W##1,A); A=fmaf(X2,W##2,A); A=fmaf(X3,W##3,A); A=fmaf(X4,W##4,A); \
  A=fmaf(X5,W##5,A); A=fmaf(X6,W##6,A); A=fmaf(X7,W##7,A); A=fmaf(X8,W##8,A); A=fmaf(X9,W##9,A);

#define KB30(W, y0,y1,y2,y3,y4,y5,y6,y7,y8,y9,y10,y11,y12,y13,y14,y15,y16,y17,y18,y19,y20,y21,y22,y23,y24,y25,y26,y27,y28,y29) \
  ROW(a0 , W, y0 ,y1 ,y2 ,y3 ,y4 ,y5 ,y6 ,y7 ,y8 ,y9 ) \
  ROW(a1 , W, y1 ,y2 ,y3 ,y4 ,y5 ,y6 ,y7 ,y8 ,y9 ,y10) \
  ROW(a2 , W, y2 ,y3 ,y4 ,y5 ,y6 ,y7 ,y8 ,y9 ,y10,y11) \
  ROW(a3 , W, y3 ,y4 ,y5 ,y6 ,y7 ,y8 ,y9 ,y10,y11,y12) \
  ROW(a4 , W, y4 ,y5 ,y6 ,y7 ,y8 ,y9 ,y10,y11,y12,y13) \
  ROW(a5 , W, y5 ,y6 ,y7 ,y8 ,y9 ,y10,y11,y12,y13,y14) \
  ROW(a6 , W, y6 ,y7 ,y8 ,y9 ,y10,y11,y12,y13,y14,y15) \
  ROW(a7 , W, y7 ,y8 ,y9 ,y10,y11,y12,y13,y14,y15,y16) \
  ROW(a8 , W, y8 ,y9 ,y10,y11,y12,y13,y14,y15,y16,y17) \
  ROW(a9 , W, y9 ,y10,y11,y12,y13,y14,y15,y16,y17,y18) \
  ROW(a10, W, y10,y11,y12,y13,y14,y15,y16,y17,y18,y19) \
  ROW(a11, W, y11,y12,y13,y14,y15,y16,y17,y18,y19,y20) \
  ROW(a12, W, y12,y13,y14,y15,y16,y17,y18,y19,y20,y21) \
  ROW(a13, W, y13,y14,y15,y16,y17,y18,y19,y20,y21,y22) \
  ROW(a14, W, y14,y15,y16,y17,y18,y19,y20,y21,y22,y23) \
  ROW(a15, W, y15,y16,y17,y18,y19,y20,y21,y22,y23,y24) \
  ROW(a16, W, y16,y17,y18,y19,y20,y21,y22,y23,y24,y25) \
  ROW(a17, W, y17,y18,y19,y20,y21,y22,y23,y24,y25,y26) \
  ROW(a18, W, y18,y19,y20,y21,y22,y23,y24,y25,y26,y27) \
  ROW(a19, W, y19,y20,y21,y22,y23,y24,y25,y26,y27,y28) \
  ROW(a20, W, y20,y21,y22,y23,y24,y25,y26,y27,y28,y29)

#define KB30X(...) KB30(__VA_ARGS__)

#define GA xa0,xa1,xa2,xa3,xa4,xa5,xa6,xa7,xa8,xa9
#define GB xb0,xb1,xb2,xb3,xb4,xb5,xb6,xb7,xb8,xb9
#define GC xc0,xc1,xc2,xc3,xc4,xc5,xc6,xc7,xc8,xc9
#define GD xd0,xd1,xd2,xd3,xd4,xd5,xd6,xd7,xd8,xd9

// ---- kernel 1: weight transposes (round-8 verbatim) ------------------------
__global__ __launch_bounds__(256)
void transpose_w(const float* __restrict__ conv_w, const float* __restrict__ fc_w,
                 float* __restrict__ wt, float* __restrict__ fct) {
    const int i = blockIdx.x * 256 + threadIdx.x;
    if (i < XD * KS) {
        const int f = i / KS;
        const int k = i - f * KS;
        wt[k * XD + f] = conv_w[i];
    }
    if (i < YOUT * XD) {
        const int o = i >> 8;
        const int q = i & 255;
        fct[q * YOUT + o] = fc_w[i];
    }
}

// ---- kernel 2: conv, NT float4 staging -> LDS, then R13 compute body -------
// Tests whether post-nt reads are REQUEST-WIDTH limited: 16 B/lane NT loads
// (1 KB/wave/instr, 1120 requests/block) vs R16's 4 B/lane (4480 requests).
__global__ __launch_bounds__(256, 2)
void conv_kernel(const float* __restrict__ seq, const float* __restrict__ wt,
                 float* __restrict__ feat) {
    extern __shared__ float ldsx[];          // 70 rows x 256 floats = 71,680 B
    const int tid = threadIdx.x;
    const int b   = blockIdx.x;
    const float* wtp = wt + tid;

    // stage: 4480 f4v, thread does idx = tid, tid+256, ... (18 rounds)
    {
        const f4v* s4 = reinterpret_cast<const f4v*>(
            seq + ((size_t)b * T_FULL + T0) * XD);
        f4v* l4 = reinterpret_cast<f4v*>(ldsx);
#pragma unroll
        for (int i = 0; i < 18; ++i) {
            const int idx = i * 256 + tid;
            if (idx < NF4) {
                const f4v v = __builtin_nontemporal_load(s4 + idx);
                l4[idx] = v;                 // ds_write_b128, linear
            }
        }
    }
    __syncthreads();

    float a0=0,a1=0,a2=0,a3=0,a4=0,a5=0,a6=0,a7=0,a8=0,a9=0,a10=0,
          a11=0,a12=0,a13=0,a14=0,a15=0,a16=0,a17=0,a18=0,a19=0,a20=0;
    DECLG(xa) DECLG(xb) DECLG(xc) DECLG(xd)
    DECLG(wa) DECLG(wb) DECLG(wc)
    LOADWSET(wa, 0); LOADWSET(wb, 10);

    LOADL(xa, 0) LOADL(xb, 10) LOADL(xc, 20)
    KB30X(wa, GA, GB, GC)                     // taps 0-9,   rows 0-29
    LOADWSET(wc, 20);
    LOADL(xd, 30)
    KB30X(wb, GB, GC, GD)                     // taps 10-19, rows 10-39
    LOADWSET(wa, 30);
    LOADL(xa, 40)
    KB30X(wc, GC, GD, GA)                     // taps 20-29, rows 20-49
    LOADWSET(wb, 40);
    LOADL(xb, 50)
    KB30X(wa, GD, GA, GB)                     // taps 30-39, rows 30-59
    LOADL(xc, 60)
    KB30X(wb, GA, GB, GC)                     // taps 40-49, rows 40-69

    float m = 0.f;   // max(relu) == max(0, max_t)
    m=fmaxf(m,a0 ); m=fmaxf(m,a1 ); m=fmaxf(m,a2 ); m=fmaxf(m,a3 ); m=fmaxf(m,a4 );
    m=fmaxf(m,a5 ); m=fmaxf(m,a6 ); m=fmaxf(m,a7 ); m=fmaxf(m,a8 ); m=fmaxf(m,a9 );
    m=fmaxf(m,a10); m=fmaxf(m,a11); m=fmaxf(m,a12); m=fmaxf(m,a13); m=fmaxf(m,a14);
    m=fmaxf(m,a15); m=fmaxf(m,a16); m=fmaxf(m,a17); m=fmaxf(m,a18); m=fmaxf(m,a19);
    m=fmaxf(m,a20);
    feat[(size_t)b * XD + tid] = m;
}

// ---- kernel 3: FC (round-8 verbatim, the 183.7 config) ---------------------
#define FCSTEP(C, NB_) C = fmaf(wv_, fb[(NB_) * XD + q], C);

__global__ __launch_bounds__(320, 2)
void fc_kernel(const float* __restrict__ feat, const float* __restrict__ fct,
               float* __restrict__ out) {
    const int o  = threadIdx.x;
    const int b0 = blockIdx.x * FC_NB;
    if (o >= YOUT) return;

    const float* fb = feat + (size_t)b0 * XD;

    float c0=0,c1=0,c2=0,c3=0,c4=0,c5=0,c6=0,c7=0,
          c8=0,c9=0,c10=0,c11=0,c12=0,c13=0,c14=0,c15=0;

#pragma unroll 2
    for (int q = 0; q < XD; ++q) {
        const float wv_ = fct[q * YOUT + o];   // coalesced across lanes
        FCSTEP(c0 , 0)  FCSTEP(c1 , 1)  FCSTEP(c2 , 2)  FCSTEP(c3 , 3)
        FCSTEP(c4 , 4)  FCSTEP(c5 , 5)  FCSTEP(c6 , 6)  FCSTEP(c7 , 7)
        FCSTEP(c8 , 8)  FCSTEP(c9 , 9)  FCSTEP(c10,10)  FCSTEP(c11,11)
        FCSTEP(c12,12)  FCSTEP(c13,13)  FCSTEP(c14,14)  FCSTEP(c15,15)
    }

    out[(size_t)(b0 +  0) * YOUT + o] = c0;
    out[(size_t)(b0 +  1) * YOUT + o] = c1;
    out[(size_t)(b0 +  2) * YOUT + o] = c2;
    out[(size_t)(b0 +  3) * YOUT + o] = c3;
    out[(size_t)(b0 +  4) * YOUT + o] = c4;
    out[(size_t)(b0 +  5) * YOUT + o] = c5;
    out[(size_t)(b0 +  6) * YOUT + o] = c6;
    out[(size_t)(b0 +  7) * YOUT + o] = c7;
    out[(size_t)(b0 +  8) * YOUT + o] = c8;
    out[(size_t)(b0 +  9) * YOUT + o] = c9;
    out[(size_t)(b0 + 10) * YOUT + o] = c10;
    out[(size_t)(b0 + 11) * YOUT + o] = c11;
    out[(size_t)(b0 + 12) * YOUT + o] = c12;
    out[(size_t)(b0 + 13) * YOUT + o] = c13;
    out[(size_t)(b0 + 14) * YOUT + o] = c14;
    out[(size_t)(b0 + 15) * YOUT + o] = c15;
}

extern "C" void kernel_launch(void* const* d_in, const int* in_sizes, int n_in,
                              void* d_out, int out_size, void* d_ws, size_t ws_size,
                              hipStream_t stream) {
    const float* seq    = (const float*)d_in[0];
    const float* conv_w = (const float*)d_in[1];
    const float* fc_w   = (const float*)d_in[2];
    float*       out    = (float*)d_out;

    float* wt   = (float*)d_ws;          // [50][256]   = 51.2 KB
    float* fct  = wt  + XD * KS;         // [256][300]  = 307.2 KB
    float* feat = fct + XD * YOUT;       // [8192][256] = 8.39 MB

    transpose_w<<<dim3((YOUT * XD + 255) / 256), dim3(256), 0, stream>>>(conv_w, fc_w, wt, fct);
    conv_kernel<<<dim3(B_TOTAL), dim3(256), TW * XD * (int)sizeof(float), stream>>>(seq, wt, feat);
    fc_kernel<<<dim3(B_TOTAL / FC_NB), dim3(320), 0, stream>>>(feat, fct, out);
}

// Round 19
// 149.968 us; speedup vs baseline: 1.2705x; 1.2705x over previous
//
#include <hip/hip_runtime.h>

#define B_TOTAL 8192
#define T_FULL  100
#define XD      256
#define T0      30
#define TW      70      // time window length (30:100)
#define KS      50      // conv kernel size
#define NT      21      // TW - KS + 1 output positions
#define YOUT    300     // Y_DIM * 50
#define FC_NB   16      // batches per FC block

// ---------------- named-scalar conv machinery (no arrays, no allocas) -------
// Sliding register window: 4 groups of 10; each phase loads only the 10 NEW
// x values (70 total loads/thread = unique minimum).
// seq loads are nontemporal: 587 MB streaming through the 256 MB L3 at zero
// reuse was allocation/eviction-throttled at 3.6 TB/s; nt bypasses cache
// allocation -> 4.5 TB/s (R16: conv 165 -> 131 us, the session's one real
// memory-path lever).

#define DECLG(G) float G##0,G##1,G##2,G##3,G##4,G##5,G##6,G##7,G##8,G##9;

#define NTL(P) __builtin_nontemporal_load(P)

#define LOADG(G, K0) \
  G##0=NTL(xp+(K0+0)*XD); G##1=NTL(xp+(K0+1)*XD); G##2=NTL(xp+(K0+2)*XD); \
  G##3=NTL(xp+(K0+3)*XD); G##4=NTL(xp+(K0+4)*XD); G##5=NTL(xp+(K0+5)*XD); \
  G##6=NTL(xp+(K0+6)*XD); G##7=NTL(xp+(K0+7)*XD); G##8=NTL(xp+(K0+8)*XD); \
  G##9=NTL(xp+(K0+9)*XD);

#define LOADW(K0) \
  w0=wtp[(K0+0)*XD]; w1=wtp[(K0+1)*XD]; w2=wtp[(K0+2)*XD]; w3=wtp[(K0+3)*XD]; w4=wtp[(K0+4)*XD]; \
  w5=wtp[(K0+5)*XD]; w6=wtp[(K0+6)*XD]; w7=wtp[(K0+7)*XD]; w8=wtp[(K0+8)*XD]; w9=wtp[(K0+9)*XD];

#define ROW(A, X0,X1,X2,X3,X4,X5,X6,X7,X8,X9) \
  A=fmaf(X0,w0,A); A=fmaf(X1,w1,A); A=fmaf(X2,w2,A); A=fmaf(X3,w3,A); A=fmaf(X4,w4,A); \
  A=fmaf(X5,w5,A); A=fmaf(X6,w6,A); A=fmaf(X7,w7,A); A=fmaf(X8,w8,A); A=fmaf(X9,w9,A);

#define KB30(y0,y1,y2,y3,y4,y5,y6,y7,y8,y9,y10,y11,y12,y13,y14,y15,y16,y17,y18,y19,y20,y21,y22,y23,y24,y25,y26,y27,y28,y29) \
  ROW(a0 , y0 ,y1 ,y2 ,y3 ,y4 ,y5 ,y6 ,y7 ,y8 ,y9 ) \
  ROW(a1 , y1 ,y2 ,y3 ,y4 ,y5 ,y6 ,y7 ,y8 ,y9 ,y10) \
  ROW(a2 , y2 ,y3 ,y4 ,y5 ,y6 ,y7 ,y8 ,y9 ,y10,y11) \
  ROW(a3 , y3 ,y4 ,y5 ,y6 ,y7 ,y8 ,y9 ,y10,y11,y12) \
  ROW(a4 , y4 ,y5 ,y6 ,y7 ,y8 ,y9 ,y10,y11,y12,y13) \
  ROW(a5 , y5 ,y6 ,y7 ,y8 ,y9 ,y10,y11,y12,y13,y14) \
  ROW(a6 , y6 ,y7 ,y8 ,y9 ,y10,y11,y12,y13,y14,y15) \
  ROW(a7 , y7 ,y8 ,y9 ,y10,y11,y12,y13,y14,y15,y16) \
  ROW(a8 , y8 ,y9 ,y10,y11,y12,y13,y14,y15,y16,y17) \
  ROW(a9 , y9 ,y10,y11,y12,y13,y14,y15,y16,y17,y18) \
  ROW(a10, y10,y11,y12,y13,y14,y15,y16,y17,y18,y19) \
  ROW(a11, y11,y12,y13,y14,y15,y16,y17,y18,y19,y20) \
  ROW(a12, y12,y13,y14,y15,y16,y17,y18,y19,y20,y21) \
  ROW(a13, y13,y14,y15,y16,y17,y18,y19,y20,y21,y22) \
  ROW(a14, y14,y15,y16,y17,y18,y19,y20,y21,y22,y23) \
  ROW(a15, y15,y16,y17,y18,y19,y20,y21,y22,y23,y24) \
  ROW(a16, y16,y17,y18,y19,y20,y21,y22,y23,y24,y25) \
  ROW(a17, y17,y18,y19,y20,y21,y22,y23,y24,y25,y26) \
  ROW(a18, y18,y19,y20,y21,y22,y23,y24,y25,y26,y27) \
  ROW(a19, y19,y20,y21,y22,y23,y24,y25,y26,y27,y28) \
  ROW(a20, y20,y21,y22,y23,y24,y25,y26,y27,y28,y29)

#define KB30X(...) KB30(__VA_ARGS__)

#define GA xa0,xa1,xa2,xa3,xa4,xa5,xa6,xa7,xa8,xa9
#define GB xb0,xb1,xb2,xb3,xb4,xb5,xb6,xb7,xb8,xb9
#define GC xc0,xc1,xc2,xc3,xc4,xc5,xc6,xc7,xc8,xc9
#define GD xd0,xd1,xd2,xd3,xd4,xd5,xd6,xd7,xd8,xd9

// ---- kernel 1: weight transposes (round-8 verbatim) ------------------------
__global__ __launch_bounds__(256)
void transpose_w(const float* __restrict__ conv_w, const float* __restrict__ fc_w,
                 float* __restrict__ wt, float* __restrict__ fct) {
    const int i = blockIdx.x * 256 + threadIdx.x;
    if (i < XD * KS) {
        const int f = i / KS;
        const int k = i - f * KS;
        wt[k * XD + f] = conv_w[i];
    }
    if (i < YOUT * XD) {
        const int o = i >> 8;
        const int q = i & 255;
        fct[q * YOUT + o] = fc_w[i];
    }
}

// ---- kernel 2: conv (R10 structure + nontemporal seq loads; R16 = 150 us) --
__global__ __launch_bounds__(256, 4)
void conv_kernel(const float* __restrict__ seq, const float* __restrict__ wt,
                 float* __restrict__ feat) {
    const int f = threadIdx.x;
    const int b = blockIdx.x;
    const float* xp  = seq + ((size_t)b * T_FULL + T0) * XD + f;
    const float* wtp = wt + f;

    float a0=0,a1=0,a2=0,a3=0,a4=0,a5=0,a6=0,a7=0,a8=0,a9=0,a10=0,
          a11=0,a12=0,a13=0,a14=0,a15=0,a16=0,a17=0,a18=0,a19=0,a20=0;
    DECLG(xa) DECLG(xb) DECLG(xc) DECLG(xd)
    float w0,w1,w2,w3,w4,w5,w6,w7,w8,w9;

    LOADW(0);  LOADG(xa, 0) LOADG(xb, 10) LOADG(xc, 20)
    KB30X(GA, GB, GC)                      // taps 0..9,   window [0..29]
    LOADG(xd, 30) LOADW(10);
    KB30X(GB, GC, GD)                      // taps 10..19, window [10..39]
    LOADG(xa, 40) LOADW(20);
    KB30X(GC, GD, GA)                      // taps 20..29, window [20..49]
    LOADG(xb, 50) LOADW(30);
    KB30X(GD, GA, GB)                      // taps 30..39, window [30..59]
    LOADG(xc, 60) LOADW(40);
    KB30X(GA, GB, GC)                      // taps 40..49, window [40..69]

    float m = 0.f;   // max(relu) == max(0, max_t)
    m=fmaxf(m,a0 ); m=fmaxf(m,a1 ); m=fmaxf(m,a2 ); m=fmaxf(m,a3 ); m=fmaxf(m,a4 );
    m=fmaxf(m,a5 ); m=fmaxf(m,a6 ); m=fmaxf(m,a7 ); m=fmaxf(m,a8 ); m=fmaxf(m,a9 );
    m=fmaxf(m,a10); m=fmaxf(m,a11); m=fmaxf(m,a12); m=fmaxf(m,a13); m=fmaxf(m,a14);
    m=fmaxf(m,a15); m=fmaxf(m,a16); m=fmaxf(m,a17); m=fmaxf(m,a18); m=fmaxf(m,a19);
    m=fmaxf(m,a20);
    feat[(size_t)b * XD + f] = m;
}

// ---- kernel 3: FC (round-8 verbatim) ---------------------------------------
#define FCSTEP(C, NB_) C = fmaf(wv_, fb[(NB_) * XD + q], C);

__global__ __launch_bounds__(320, 2)
void fc_kernel(const float* __restrict__ feat, const float* __restrict__ fct,
               float* __restrict__ out) {
    const int o  = threadIdx.x;
    const int b0 = blockIdx.x * FC_NB;
    if (o >= YOUT) return;

    const float* fb = feat + (size_t)b0 * XD;

    float c0=0,c1=0,c2=0,c3=0,c4=0,c5=0,c6=0,c7=0,
          c8=0,c9=0,c10=0,c11=0,c12=0,c13=0,c14=0,c15=0;

#pragma unroll 2
    for (int q = 0; q < XD; ++q) {
        const float wv_ = fct[q * YOUT + o];   // coalesced across lanes
        FCSTEP(c0 , 0)  FCSTEP(c1 , 1)  FCSTEP(c2 , 2)  FCSTEP(c3 , 3)
        FCSTEP(c4 , 4)  FCSTEP(c5 , 5)  FCSTEP(c6 , 6)  FCSTEP(c7 , 7)
        FCSTEP(c8 , 8)  FCSTEP(c9 , 9)  FCSTEP(c10,10)  FCSTEP(c11,11)
        FCSTEP(c12,12)  FCSTEP(c13,13)  FCSTEP(c14,14)  FCSTEP(c15,15)
    }

    out[(size_t)(b0 +  0) * YOUT + o] = c0;
    out[(size_t)(b0 +  1) * YOUT + o] = c1;
    out[(size_t)(b0 +  2) * YOUT + o] = c2;
    out[(size_t)(b0 +  3) * YOUT + o] = c3;
    out[(size_t)(b0 +  4) * YOUT + o] = c4;
    out[(size_t)(b0 +  5) * YOUT + o] = c5;
    out[(size_t)(b0 +  6) * YOUT + o] = c6;
    out[(size_t)(b0 +  7) * YOUT + o] = c7;
    out[(size_t)(b0 +  8) * YOUT + o] = c8;
    out[(size_t)(b0 +  9) * YOUT + o] = c9;
    out[(size_t)(b0 + 10) * YOUT + o] = c10;
    out[(size_t)(b0 + 11) * YOUT + o] = c11;
    out[(size_t)(b0 + 12) * YOUT + o] = c12;
    out[(size_t)(b0 + 13) * YOUT + o] = c13;
    out[(size_t)(b0 + 14) * YOUT + o] = c14;
    out[(size_t)(b0 + 15) * YOUT + o] = c15;
}

extern "C" void kernel_launch(void* const* d_in, const int* in_sizes, int n_in,
                              void* d_out, int out_size, void* d_ws, size_t ws_size,
                              hipStream_t stream) {
    const float* seq    = (const float*)d_in[0];
    const float* conv_w = (const float*)d_in[1];
    const float* fc_w   = (const float*)d_in[2];
    float*       out    = (float*)d_out;

    float* wt   = (float*)d_ws;          // [50][256]   = 51.2 KB
    float* fct  = wt  + XD * KS;         // [256][300]  = 307.2 KB
    float* feat = fct + XD * YOUT;       // [8192][256] = 8.39 MB

    transpose_w<<<dim3((YOUT * XD + 255) / 256), dim3(256), 0, stream>>>(conv_w, fc_w, wt, fct);
    conv_kernel<<<dim3(B_TOTAL), dim3(256), 0, stream>>>(seq, wt, feat);
    fc_kernel<<<dim3(B_TOTAL / FC_NB), dim3(320), 0, stream>>>(feat, fct, out);
}